// Round 4
// baseline (586.527 us; speedup 1.0000x reference)
//
#include <hip/hip_runtime.h>
#include <hip/hip_bf16.h>

#define NEXP 8
#define DD 256

typedef __attribute__((ext_vector_type(8))) short  bf16x8;
typedef __attribute__((ext_vector_type(4))) float  f32x4;

__device__ __forceinline__ unsigned short f2bf(float f) {
    union { float f; unsigned int u; } v; v.f = f;
    unsigned int r = (v.u + 0x7FFFu + ((v.u >> 16) & 1u)) >> 16;
    return (unsigned short)r;
}

__device__ __forceinline__ float gelu_exact(float x) {
    return 0.5f * x * (1.0f + erff(x * 0.70710678118654752f));
}

// ---------------- weight prep: fp32 [e][k][n] -> bf16 transposed [e][n][k] ----
__global__ __launch_bounds__(256)
void prep_weights(const float* __restrict__ w1, const float* __restrict__ w2,
                  unsigned short* __restrict__ w1t, unsigned short* __restrict__ w2t)
{
    int idx = blockIdx.x * 256 + threadIdx.x;      // over NEXP*DD*DD = 524288
    int e = idx >> 16;
    int k = (idx >> 8) & 255;
    int n = idx & 255;
    int oidx = (((e << 8) | n) << 8) | k;
    w1t[oidx] = f2bf(w1[idx]);
    w2t[oidx] = f2bf(w2[idx]);
}

// ---------------- router: wave-per-token fp32 logits + top2 ------------------
__global__ __launch_bounds__(256)
void router_kernel(const float* __restrict__ X, const float* __restrict__ RW,
                   unsigned int* __restrict__ re, float* __restrict__ rwgt, int N)
{
    __shared__ float rws[NEXP * DD];
    const int tid = threadIdx.x;
    for (int i = tid; i < NEXP * DD / 4; i += 256)
        ((float4*)rws)[i] = ((const float4*)RW)[i];
    __syncthreads();
    const int wave = tid >> 6, lane = tid & 63;
    const int t = blockIdx.x * 4 + wave;
    if (t >= N) return;

    float4 xv = *(const float4*)(X + (size_t)t * DD + lane * 4);
    float lg[NEXP];
    #pragma unroll
    for (int e = 0; e < NEXP; ++e) {
        float4 wv = *(const float4*)(rws + e * DD + lane * 4);
        lg[e] = xv.x * wv.x + xv.y * wv.y + xv.z * wv.z + xv.w * wv.w;
    }
    #pragma unroll
    for (int e = 0; e < NEXP; ++e) {
        #pragma unroll
        for (int off = 32; off; off >>= 1)
            lg[e] += __shfl_xor(lg[e], off);
    }
    // top-2 (ties -> lowest index, matches jax top_k)
    int e0 = 0; float l0 = lg[0];
    #pragma unroll
    for (int e = 1; e < NEXP; ++e) if (lg[e] > l0) { l0 = lg[e]; e0 = e; }
    int e1 = -1; float l1 = -3.4e38f;
    #pragma unroll
    for (int e = 0; e < NEXP; ++e) if (e != e0 && lg[e] > l1) { l1 = lg[e]; e1 = e; }
    float d  = expf(l1 - l0);           // <= 1, stable
    float w0 = 1.0f / (1.0f + d);
    float w1v = d / (1.0f + d);
    if (lane == 0) {
        re[t] = (unsigned int)e0 | ((unsigned int)e1 << 8);
        rwgt[2 * t + 0] = w0;
        rwgt[2 * t + 1] = w1v;
    }
}

// ---------------- list build: wave-aggregated compaction ---------------------
__global__ __launch_bounds__(256)
void build_lists(const unsigned int* __restrict__ re, unsigned int* __restrict__ lists,
                 int* __restrict__ cnt, int N)
{
    int t = blockIdx.x * 256 + threadIdx.x;
    unsigned int r = (t < N) ? re[t] : 0xFFFFu;   // e=0xFF never matches
    int lane = threadIdx.x & 63;
    unsigned long long ltmask = (1ull << lane) - 1ull;
    #pragma unroll
    for (int slot = 0; slot < 2; ++slot) {
        int e = (r >> (slot * 8)) & 0xFF;
        for (int ee = 0; ee < NEXP; ++ee) {
            unsigned long long mask = __ballot(e == ee);
            if (mask == 0ull) continue;                      // wave-uniform
            int leader = __ffsll(mask) - 1;
            int nw = __popcll(mask);
            int base = 0;
            if (lane == leader) base = atomicAdd(&cnt[slot * NEXP + ee], nw);
            base = __shfl(base, leader);
            if (e == ee) {
                int pre = __popcll(mask & ltmask);
                lists[(size_t)(slot * NEXP + ee) * N + base + pre] = (unsigned int)t;
            }
        }
    }
}

// ---------------- expert pass: fused GEMM1 -> gelu -> GEMM2 -> scatter -------
// one block = 64 tokens of expert e (slot PASS). 256 threads / 4 waves.
// wave w computes cols [64w, 64w+64) for all 64 rows.
template<int PASS>
__global__ __launch_bounds__(256, 2)
void expert_pass(const float* __restrict__ X, float* __restrict__ Out,
                 const unsigned short* __restrict__ W1t, const unsigned short* __restrict__ W2t,
                 const float* __restrict__ B1, const float* __restrict__ B2,
                 const unsigned int* __restrict__ lists, const float* __restrict__ rwgt,
                 const int* __restrict__ cnt, int N)
{
    const int e = blockIdx.y;
    const int count = cnt[PASS * NEXP + e];
    const int m0 = blockIdx.x * 64;
    if (m0 >= count) return;

    __shared__ unsigned char lds[65536];          // Xs 32K | Hs 32K (bf16, swizzled)
    unsigned char* Xs = lds;
    unsigned char* Hs = lds + 32768;

    const int tid = threadIdx.x;
    const unsigned int* listE = lists + (size_t)(PASS * NEXP + e) * N;

    // ---- stage X tile (fp32 -> bf16, XOR-swizzled rows) ----
    #pragma unroll
    for (int i = 0; i < 16; ++i) {
        int id = i * 256 + tid;                   // 4096 float4 = 64 rows x 64
        int row = id >> 6;
        int c4 = id & 63;
        int m = m0 + row;
        float4 v = make_float4(0.f, 0.f, 0.f, 0.f);
        if (m < count) {
            unsigned int t = listE[m];
            v = *(const float4*)(X + (size_t)t * DD + c4 * 4);
        }
        uint2 p;
        p.x = (unsigned int)f2bf(v.x) | ((unsigned int)f2bf(v.y) << 16);
        p.y = (unsigned int)f2bf(v.z) | ((unsigned int)f2bf(v.w) << 16);
        int byte = row * 512 + c4 * 8;
        byte ^= (row & 7) << 4;
        *(uint2*)(Xs + byte) = p;
    }
    __syncthreads();

    const int wv = tid >> 6;
    const int lane = tid & 63;
    const int c0 = wv * 64;
    const int lrow = lane & 15;
    const int lk = (lane >> 4) * 8;

    // ---- GEMM1: H = gelu(X @ W1 + b1) ----
    f32x4 acc[4][4] = {};
    const unsigned short* W1e = W1t + (size_t)e * DD * DD;
    for (int kk = 0; kk < 8; ++kk) {
        int kbase = kk * 32 + lk;
        bf16x8 a[4], b[4];
        #pragma unroll
        for (int rf = 0; rf < 4; ++rf) {
            int row = rf * 16 + lrow;
            int byte = (row * 512 + kbase * 2) ^ ((row & 7) << 4);
            a[rf] = *(const bf16x8*)(Xs + byte);
        }
        #pragma unroll
        for (int cf = 0; cf < 4; ++cf) {
            int col = c0 + cf * 16 + lrow;
            b[cf] = *(const bf16x8*)(W1e + (size_t)col * DD + kbase);
        }
        #pragma unroll
        for (int rf = 0; rf < 4; ++rf)
            #pragma unroll
            for (int cf = 0; cf < 4; ++cf)
                acc[rf][cf] = __builtin_amdgcn_mfma_f32_16x16x32_bf16(a[rf], b[cf], acc[rf][cf], 0, 0, 0);
    }

    // ---- epilogue 1: bias + gelu -> Hs (bf16, swizzled) ----
    #pragma unroll
    for (int cf = 0; cf < 4; ++cf) {
        int col = c0 + cf * 16 + lrow;
        float bias = B1[e * DD + col];
        #pragma unroll
        for (int rf = 0; rf < 4; ++rf) {
            #pragma unroll
            for (int j = 0; j < 4; ++j) {
                int row = rf * 16 + (lane >> 4) * 4 + j;
                float h = gelu_exact(acc[rf][cf][j] + bias);
                int byte = (row * 512 + col * 2) ^ ((row & 7) << 4);
                *(unsigned short*)(Hs + byte) = f2bf(h);
            }
        }
    }
    __syncthreads();

    // ---- GEMM2: Y = H @ W2 ----
    f32x4 acc2[4][4] = {};
    const unsigned short* W2e = W2t + (size_t)e * DD * DD;
    for (int kk = 0; kk < 8; ++kk) {
        int kbase = kk * 32 + lk;
        bf16x8 a[4], b[4];
        #pragma unroll
        for (int rf = 0; rf < 4; ++rf) {
            int row = rf * 16 + lrow;
            int byte = (row * 512 + kbase * 2) ^ ((row & 7) << 4);
            a[rf] = *(const bf16x8*)(Hs + byte);
        }
        #pragma unroll
        for (int cf = 0; cf < 4; ++cf) {
            int col = c0 + cf * 16 + lrow;
            b[cf] = *(const bf16x8*)(W2e + (size_t)col * DD + kbase);
        }
        #pragma unroll
        for (int rf = 0; rf < 4; ++rf)
            #pragma unroll
            for (int cf = 0; cf < 4; ++cf)
                acc2[rf][cf] = __builtin_amdgcn_mfma_f32_16x16x32_bf16(a[rf], b[cf], acc2[rf][cf], 0, 0, 0);
    }

    // ---- epilogue 2: bias + weighted scatter (no atomics: one pass per slot) ----
    #pragma unroll
    for (int rf = 0; rf < 4; ++rf) {
        #pragma unroll
        for (int j = 0; j < 4; ++j) {
            int row = rf * 16 + (lane >> 4) * 4 + j;
            int m = m0 + row;
            if (m < count) {
                unsigned int t = listE[m];
                float wgt = rwgt[2 * t + PASS];
                #pragma unroll
                for (int cf = 0; cf < 4; ++cf) {
                    int col = c0 + cf * 16 + lrow;
                    float y = acc2[rf][cf][j] + B2[e * DD + col];
                    size_t idx = (size_t)t * DD + col;
                    if (PASS == 0) Out[idx] = X[idx] + wgt * y;
                    else           Out[idx] += wgt * y;
                }
            }
        }
    }
}

// ---------------- launch -----------------------------------------------------
extern "C" void kernel_launch(void* const* d_in, const int* in_sizes, int n_in,
                              void* d_out, int out_size, void* d_ws, size_t ws_size,
                              hipStream_t stream) {
    const float* X  = (const float*)d_in[0];
    const float* RW = (const float*)d_in[1];
    const float* W1 = (const float*)d_in[2];
    const float* B1 = (const float*)d_in[3];
    const float* W2 = (const float*)d_in[4];
    const float* B2 = (const float*)d_in[5];
    float* Out = (float*)d_out;
    const int N = in_sizes[0] / DD;               // 65536 tokens

    unsigned char* w = (unsigned char*)d_ws;
    size_t off = 0;
    int* cnt = (int*)(w + off);                   off += 256;
    unsigned int* re = (unsigned int*)(w + off);  off += (size_t)N * 4;
    float* rwgt = (float*)(w + off);              off += (size_t)N * 8;
    unsigned int* lists = (unsigned int*)(w + off); off += (size_t)2 * NEXP * N * 4;
    unsigned short* w1t = (unsigned short*)(w + off); off += (size_t)NEXP * DD * DD * 2;
    unsigned short* w2t = (unsigned short*)(w + off); off += (size_t)NEXP * DD * DD * 2;

    hipMemsetAsync(cnt, 0, 256, stream);
    prep_weights<<<NEXP * DD * DD / 256, 256, 0, stream>>>(W1, W2, w1t, w2t);
    router_kernel<<<(N + 3) / 4, 256, 0, stream>>>(X, RW, re, rwgt, N);
    build_lists<<<(N + 255) / 256, 256, 0, stream>>>(re, lists, cnt, N);
    dim3 grid((N + 63) / 64, NEXP);
    expert_pass<0><<<grid, 256, 0, stream>>>(X, Out, w1t, w2t, B1, B2, lists, rwgt, cnt, N);
    expert_pass<1><<<grid, 256, 0, stream>>>(X, Out, w1t, w2t, B1, B2, lists, rwgt, cnt, N);
}

// Round 7
// 415.964 us; speedup vs baseline: 1.4100x; 1.4100x over previous
//
#include <hip/hip_runtime.h>
#include <hip/hip_bf16.h>

#define NEXP 8
#define DD 256

typedef __attribute__((ext_vector_type(8))) short  bf16x8;
typedef __attribute__((ext_vector_type(4))) float  f32x4;

__device__ __forceinline__ unsigned short f2bf(float f) {
    union { float f; unsigned int u; } v; v.f = f;
    unsigned int r = (v.u + 0x7FFFu + ((v.u >> 16) & 1u)) >> 16;
    return (unsigned short)r;
}

__device__ __forceinline__ float gelu_exact(float x) {
    return 0.5f * x * (1.0f + erff(x * 0.70710678118654752f));
}

// ---- weight prep v2: LDS 64x64 transpose, coalesced both sides --------------
// grid 256: blockIdx>>7 selects w1/w2; then e(3b) | ko(2b) | no(2b)
__global__ __launch_bounds__(256)
void prep_weights(const float* __restrict__ w1, const float* __restrict__ w2,
                  unsigned short* __restrict__ w1t, unsigned short* __restrict__ w2t)
{
    __shared__ float tile[64][65];
    const int m  = blockIdx.x >> 7;
    const int e  = (blockIdx.x >> 4) & 7;
    const int ko = (blockIdx.x >> 2) & 3;
    const int no = blockIdx.x & 3;
    const float* src = m ? w2 : w1;
    unsigned short* dst = m ? w2t : w1t;
    const size_t base = ((size_t)e << 16);

    #pragma unroll
    for (int i = 0; i < 16; ++i) {
        int r = i * 4 + (threadIdx.x >> 6);
        int c = threadIdx.x & 63;
        tile[r][c] = src[base + (size_t)(ko * 64 + r) * DD + no * 64 + c];
    }
    __syncthreads();
    #pragma unroll
    for (int i = 0; i < 8; ++i) {
        int n  = i * 8 + (threadIdx.x >> 5);
        int k2 = (threadIdx.x & 31) * 2;
        unsigned int val = (unsigned int)f2bf(tile[k2][n])
                         | ((unsigned int)f2bf(tile[k2 + 1][n]) << 16);
        *(unsigned int*)(dst + base + (size_t)(no * 64 + n) * DD + ko * 64 + k2) = val;
    }
}

// ---- router v2: 64 tokens/block, fused per-block histogram (LDS atomics) ----
__global__ __launch_bounds__(256)
void router_kernel(const float* __restrict__ X, const float* __restrict__ RW,
                   unsigned int* __restrict__ re, float* __restrict__ rwgt,
                   int* __restrict__ bcnt, int N)
{
    __shared__ float rws[NEXP * DD];
    __shared__ int hist[16];
    const int tid = threadIdx.x;
    if (tid < 16) hist[tid] = 0;
    for (int i = tid; i < NEXP * DD / 4; i += 256)
        ((float4*)rws)[i] = ((const float4*)RW)[i];
    __syncthreads();
    const int wave = tid >> 6, lane = tid & 63;

    for (int it = 0; it < 16; ++it) {
        int t = blockIdx.x * 64 + wave * 16 + it;
        float4 xv = *(const float4*)(X + (size_t)t * DD + lane * 4);
        float lg[NEXP];
        #pragma unroll
        for (int e = 0; e < NEXP; ++e) {
            float4 wv = *(const float4*)(rws + e * DD + lane * 4);
            lg[e] = xv.x * wv.x + xv.y * wv.y + xv.z * wv.z + xv.w * wv.w;
        }
        #pragma unroll
        for (int e = 0; e < NEXP; ++e) {
            #pragma unroll
            for (int off = 32; off; off >>= 1)
                lg[e] += __shfl_xor(lg[e], off);
        }
        int e0 = 0; float l0 = lg[0];
        #pragma unroll
        for (int e = 1; e < NEXP; ++e) if (lg[e] > l0) { l0 = lg[e]; e0 = e; }
        int e1 = -1; float l1 = -3.4e38f;
        #pragma unroll
        for (int e = 0; e < NEXP; ++e) if (e != e0 && lg[e] > l1) { l1 = lg[e]; e1 = e; }
        float d   = expf(l1 - l0);
        float w0  = 1.0f / (1.0f + d);
        float w1v = d / (1.0f + d);
        if (lane == 0) {
            re[t] = (unsigned int)e0 | ((unsigned int)e1 << 8);
            rwgt[2 * t + 0] = w0;
            rwgt[2 * t + 1] = w1v;
            atomicAdd(&hist[e0], 1);
            atomicAdd(&hist[8 + e1], 1);
        }
    }
    __syncthreads();
    if (tid < 16) bcnt[blockIdx.x * 16 + tid] = hist[tid];
}

// ---- scan: 4:1 aggregate router blocks -> 256-token chunk bases + totals ----
__global__ void scan_kernel(const int* __restrict__ bcnt, int* __restrict__ bbase,
                            int* __restrict__ cnt, int nchunk)
{
    int j = threadIdx.x;
    if (j >= 16) return;
    int run = 0;
    for (int c = 0; c < nchunk; ++c) {
        bbase[c * 16 + j] = run;
        run += bcnt[(4 * c + 0) * 16 + j] + bcnt[(4 * c + 1) * 16 + j]
             + bcnt[(4 * c + 2) * 16 + j] + bcnt[(4 * c + 3) * 16 + j];
    }
    cnt[j] = run;
}

// ---- scatter: rank within 256-token chunk via LDS atomics, write lists ------
__global__ __launch_bounds__(256)
void scatter_kernel(const unsigned int* __restrict__ re, const int* __restrict__ bbase,
                    unsigned int* __restrict__ lists, int N)
{
    __shared__ int hist[16];
    __shared__ int base[16];
    const int tid = threadIdx.x;
    if (tid < 16) { hist[tid] = 0; base[tid] = bbase[blockIdx.x * 16 + tid]; }
    __syncthreads();
    int t = blockIdx.x * 256 + tid;
    unsigned int r = re[t];
    int e0 = r & 255, e1 = (r >> 8) & 255;
    int r0 = atomicAdd(&hist[e0], 1);
    int r1 = atomicAdd(&hist[8 + e1], 1);
    lists[(size_t)e0 * N + base[e0] + r0] = (unsigned int)t;
    lists[(size_t)(8 + e1) * N + base[8 + e1] + r1] = (unsigned int)t;
}

// ---- expert pass: fused GEMM1 -> gelu -> GEMM2 -> scatter -------------------
// 32 KiB LDS (Hs aliases Xs after GEMM1), 3 blocks/CU.
template<int PASS>
__global__ __launch_bounds__(256, 3)
void expert_pass(const float* __restrict__ X, float* __restrict__ Out,
                 const unsigned short* __restrict__ W1t, const unsigned short* __restrict__ W2t,
                 const float* __restrict__ B1, const float* __restrict__ B2,
                 const unsigned int* __restrict__ lists, const float* __restrict__ rwgt,
                 const int* __restrict__ cnt, int N)
{
    const int e = blockIdx.y;
    const int count = cnt[PASS * NEXP + e];
    const int m0 = blockIdx.x * 64;
    if (m0 >= count) return;

    __shared__ unsigned char Ts[32768];           // X tile, then H tile (aliased)

    const int tid = threadIdx.x;
    const unsigned int* listE = lists + (size_t)(PASS * NEXP + e) * N;

    // ---- stage X tile (fp32 -> bf16, XOR-swizzled rows) ----
    #pragma unroll
    for (int i = 0; i < 16; ++i) {
        int id = i * 256 + tid;                   // 4096 float4 = 64 rows x 64
        int row = id >> 6;
        int c4 = id & 63;
        int m = m0 + row;
        float4 v = make_float4(0.f, 0.f, 0.f, 0.f);
        if (m < count) {
            unsigned int t = listE[m];
            v = *(const float4*)(X + (size_t)t * DD + c4 * 4);
        }
        uint2 p;
        p.x = (unsigned int)f2bf(v.x) | ((unsigned int)f2bf(v.y) << 16);
        p.y = (unsigned int)f2bf(v.z) | ((unsigned int)f2bf(v.w) << 16);
        int byte = row * 512 + c4 * 8;
        byte ^= (row & 7) << 4;
        *(uint2*)(Ts + byte) = p;
    }
    __syncthreads();

    const int wv = tid >> 6;
    const int lane = tid & 63;
    const int c0 = wv * 64;
    const int lrow = lane & 15;
    const int lk = (lane >> 4) * 8;

    // ---- GEMM1: H = gelu(X @ W1 + b1) ----
    f32x4 acc[4][4] = {};
    const unsigned short* W1e = W1t + (size_t)e * DD * DD;
    for (int kk = 0; kk < 8; ++kk) {
        int kbase = kk * 32 + lk;
        bf16x8 a[4], b[4];
        #pragma unroll
        for (int rf = 0; rf < 4; ++rf) {
            int row = rf * 16 + lrow;
            int byte = (row * 512 + kbase * 2) ^ ((row & 7) << 4);
            a[rf] = *(const bf16x8*)(Ts + byte);
        }
        #pragma unroll
        for (int cf = 0; cf < 4; ++cf) {
            int col = c0 + cf * 16 + lrow;
            b[cf] = *(const bf16x8*)(W1e + (size_t)col * DD + kbase);
        }
        #pragma unroll
        for (int rf = 0; rf < 4; ++rf)
            #pragma unroll
            for (int cf = 0; cf < 4; ++cf)
                acc[rf][cf] = __builtin_amdgcn_mfma_f32_16x16x32_bf16(a[rf], b[cf], acc[rf][cf], 0, 0, 0);
    }
    __syncthreads();                              // all waves done reading X tile

    // ---- epilogue 1: bias + gelu -> H tile (aliases X tile) ----
    #pragma unroll
    for (int cf = 0; cf < 4; ++cf) {
        int col = c0 + cf * 16 + lrow;
        float bias = B1[e * DD + col];
        #pragma unroll
        for (int rf = 0; rf < 4; ++rf) {
            #pragma unroll
            for (int j = 0; j < 4; ++j) {
                int row = rf * 16 + (lane >> 4) * 4 + j;
                float h = gelu_exact(acc[rf][cf][j] + bias);
                int byte = (row * 512 + col * 2) ^ ((row & 7) << 4);
                *(unsigned short*)(Ts + byte) = f2bf(h);
            }
        }
    }
    __syncthreads();

    // ---- GEMM2: Y = H @ W2 ----
    f32x4 acc2[4][4] = {};
    const unsigned short* W2e = W2t + (size_t)e * DD * DD;
    for (int kk = 0; kk < 8; ++kk) {
        int kbase = kk * 32 + lk;
        bf16x8 a[4], b[4];
        #pragma unroll
        for (int rf = 0; rf < 4; ++rf) {
            int row = rf * 16 + lrow;
            int byte = (row * 512 + kbase * 2) ^ ((row & 7) << 4);
            a[rf] = *(const bf16x8*)(Ts + byte);
        }
        #pragma unroll
        for (int cf = 0; cf < 4; ++cf) {
            int col = c0 + cf * 16 + lrow;
            b[cf] = *(const bf16x8*)(W2e + (size_t)col * DD + kbase);
        }
        #pragma unroll
        for (int rf = 0; rf < 4; ++rf)
            #pragma unroll
            for (int cf = 0; cf < 4; ++cf)
                acc2[rf][cf] = __builtin_amdgcn_mfma_f32_16x16x32_bf16(a[rf], b[cf], acc2[rf][cf], 0, 0, 0);
    }

    // ---- epilogue 2: bias + weighted scatter (no atomics: one pass per slot) ----
    #pragma unroll
    for (int rf = 0; rf < 4; ++rf) {
        #pragma unroll
        for (int j = 0; j < 4; ++j) {
            int row = rf * 16 + (lane >> 4) * 4 + j;
            int m = m0 + row;
            if (m < count) {
                unsigned int t = listE[m];
                float wgt = rwgt[2 * t + PASS];
                #pragma unroll
                for (int cf = 0; cf < 4; ++cf) {
                    int col = c0 + cf * 16 + lrow;
                    float y = acc2[rf][cf][j] + B2[e * DD + col];
                    size_t idx = (size_t)t * DD + col;
                    if (PASS == 0) Out[idx] = X[idx] + wgt * y;
                    else           Out[idx] += wgt * y;
                }
            }
        }
    }
}

// ---------------- launch -----------------------------------------------------
extern "C" void kernel_launch(void* const* d_in, const int* in_sizes, int n_in,
                              void* d_out, int out_size, void* d_ws, size_t ws_size,
                              hipStream_t stream) {
    const float* X  = (const float*)d_in[0];
    const float* RW = (const float*)d_in[1];
    const float* W1 = (const float*)d_in[2];
    const float* B1 = (const float*)d_in[3];
    const float* W2 = (const float*)d_in[4];
    const float* B2 = (const float*)d_in[5];
    float* Out = (float*)d_out;
    const int N = in_sizes[0] / DD;               // 65536 tokens

    unsigned char* w = (unsigned char*)d_ws;
    size_t off = 0;
    int* cnt = (int*)(w + off);                   off += 256;
    unsigned int* re = (unsigned int*)(w + off);  off += (size_t)N * 4;
    float* rwgt = (float*)(w + off);              off += (size_t)N * 8;
    unsigned int* lists = (unsigned int*)(w + off); off += (size_t)2 * NEXP * N * 4;
    unsigned short* w1t = (unsigned short*)(w + off); off += (size_t)NEXP * DD * DD * 2;
    unsigned short* w2t = (unsigned short*)(w + off); off += (size_t)NEXP * DD * DD * 2;
    int* bcnt  = (int*)(w + off);                 off += (size_t)(N / 64) * 16 * 4;
    int* bbase = (int*)(w + off);                 off += (size_t)(N / 256) * 16 * 4;

    prep_weights<<<256, 256, 0, stream>>>(W1, W2, w1t, w2t);
    router_kernel<<<N / 64, 256, 0, stream>>>(X, RW, re, rwgt, bcnt, N);
    scan_kernel<<<1, 64, 0, stream>>>(bcnt, bbase, cnt, N / 256);
    scatter_kernel<<<N / 256, 256, 0, stream>>>(re, bbase, lists, N);
    dim3 grid((N + 63) / 64, NEXP);
    expert_pass<0><<<grid, 256, 0, stream>>>(X, Out, w1t, w2t, B1, B2, lists, rwgt, cnt, N);
    expert_pass<1><<<grid, 256, 0, stream>>>(X, Out, w1t, w2t, B1, B2, lists, rwgt, cnt, N);
}